// Round 2
// baseline (742.311 us; speedup 1.0000x reference)
//
#include <hip/hip_runtime.h>

#define HH 128
#define WW 128
#define CC 64
#define TT 5
#define HW (HH*WW)
#define ICC 16   // input channels staged per barrier

// ---------------- conv1: 64->64 3x3 zero-pad + leaky relu ----------------
// grid (8,8, n*4+ocg), block (16,16). Each block: 16x16 tile, 16 output chans.
// 16 input channels staged in LDS per barrier pair (4 barriers total vs 64).
__global__ __launch_bounds__(256) void conv1_k(const float* __restrict__ x,
    const float* __restrict__ w1, const float* __restrict__ b1,
    float* __restrict__ y) {
  __shared__ float buf[ICC*324];
  const int tw = threadIdx.x, th = threadIdx.y;
  const int tid = th*16 + tw;
  const int wz = blockIdx.z;
  const int n = wz >> 2, ocg = (wz & 3) << 4;
  const int bi = n / 5, ti = n % 5;
  const int h0 = blockIdx.y << 4, w0 = blockIdx.x << 4;
  const float* xn = x + ((size_t)bi*CC*TT + ti) * HW;   // + ic*TT*HW

  float acc[16];
  #pragma unroll
  for (int o = 0; o < 16; ++o) acc[o] = b1[ocg + o];

  for (int icb = 0; icb < CC; icb += ICC) {
    __syncthreads();
    for (int e = tid; e < ICC*324; e += 256) {
      int ic = e / 324, r2 = e - ic*324;
      int r = r2 / 18, c = r2 - r*18;
      int gh = h0 + r - 1, gw = w0 + c - 1;
      float v = 0.f;
      if (gh >= 0 && gh < HH && gw >= 0 && gw < WW)
        v = xn[(size_t)(icb+ic)*(TT*HW) + gh*WW + gw];
      buf[e] = v;
    }
    __syncthreads();
    #pragma unroll
    for (int i2 = 0; i2 < ICC; ++i2) {
      float p[9];
      #pragma unroll
      for (int i = 0; i < 3; ++i)
        #pragma unroll
        for (int j = 0; j < 3; ++j)
          p[i*3+j] = buf[i2*324 + (th+i)*18 + tw + j];
      const float* wp = w1 + ((size_t)ocg*CC + icb + i2)*9;  // block-uniform
      #pragma unroll
      for (int o = 0; o < 16; ++o) {
        #pragma unroll
        for (int k = 0; k < 9; ++k)
          acc[o] = fmaf(wp[o*CC*9 + k], p[k], acc[o]);
      }
    }
  }
  float* yp = y + ((size_t)n*CC + ocg)*HW + (h0+th)*WW + w0 + tw;
  #pragma unroll
  for (int o = 0; o < 16; ++o) {
    float v = acc[o];
    yp[(size_t)o*HW] = (v >= 0.f) ? v : 0.2f*v;
  }
}

// ---------------- conv2: 64->9 3x3 zero-pad (raw kernel, un-normalized) ----
// grid (8,8,10), block (16,16). Output layout (n, kk, h, w).
__global__ __launch_bounds__(256) void conv2_k(const float* __restrict__ y,
    const float* __restrict__ w2, const float* __restrict__ b2,
    float* __restrict__ ker0) {
  __shared__ float buf[ICC*324];
  const int tw = threadIdx.x, th = threadIdx.y;
  const int tid = th*16 + tw;
  const int n = blockIdx.z;
  const int h0 = blockIdx.y << 4, w0 = blockIdx.x << 4;
  const float* yn = y + (size_t)n*CC*HW;

  float acc[9];
  #pragma unroll
  for (int o = 0; o < 9; ++o) acc[o] = b2[o];

  for (int icb = 0; icb < CC; icb += ICC) {
    __syncthreads();
    for (int e = tid; e < ICC*324; e += 256) {
      int ic = e / 324, r2 = e - ic*324;
      int r = r2 / 18, c = r2 - r*18;
      int gh = h0 + r - 1, gw = w0 + c - 1;
      float v = 0.f;
      if (gh >= 0 && gh < HH && gw >= 0 && gw < WW)
        v = yn[(size_t)(icb+ic)*HW + gh*WW + gw];
      buf[e] = v;
    }
    __syncthreads();
    #pragma unroll
    for (int i2 = 0; i2 < ICC; ++i2) {
      float p[9];
      #pragma unroll
      for (int i = 0; i < 3; ++i)
        #pragma unroll
        for (int j = 0; j < 3; ++j)
          p[i*3+j] = buf[i2*324 + (th+i)*18 + tw + j];
      const float* wp = w2 + (size_t)(icb+i2)*9;
      #pragma unroll
      for (int o = 0; o < 9; ++o) {
        #pragma unroll
        for (int k = 0; k < 9; ++k)
          acc[o] = fmaf(wp[o*CC*9 + k], p[k], acc[o]);
      }
    }
  }
  float* kp = ker0 + (size_t)n*9*HW + (h0+th)*WW + w0 + tw;
  #pragma unroll
  for (int o = 0; o < 9; ++o) kp[(size_t)o*HW] = acc[o];
}

// ---------------- dynamic filtering -----------------------------------------
// out[bi,ci,h,w] = sum_{ti,i,j} x_edgeclamped[bi,ci,ti,h+i-1,w+j-1]
//                               * (ker0 - mean_K + 1/45)[bi,h,w,ti*9+i*3+j]
// grid (8,8, bi*4+cig), block (16,16): 16x16 tile, 16 channels per block,
// staged 4 channels per barrier pair.
#define CHB 4
__global__ __launch_bounds__(256) void dynf_k(const float* __restrict__ x,
    const float* __restrict__ ker0, float* __restrict__ out) {
  __shared__ float xt[CHB*TT*324];   // 25.9 KB
  const int tw = threadIdx.x, th = threadIdx.y;
  const int tid = th*16 + tw;
  const int wz = blockIdx.z;
  const int bi = wz >> 2, cig = (wz & 3) << 4;
  const int h0 = blockIdx.y << 4, w0 = blockIdx.x << 4;
  const int pix = (h0+th)*WW + w0 + tw;

  // load this pixel's 45 raw kernel values, normalize in-register
  float kv[45];
  float s = 0.f;
  #pragma unroll
  for (int ti = 0; ti < TT; ++ti)
    #pragma unroll
    for (int kk = 0; kk < 9; ++kk) {
      float v = ker0[((size_t)(bi*TT + ti)*9 + kk)*HW + pix];
      kv[ti*9+kk] = v;
      s += v;
    }
  const float m = (s - 1.f) * (1.f/45.f);   // mean - 1/45
  #pragma unroll
  for (int q = 0; q < 45; ++q) kv[q] -= m;

  for (int cb = 0; cb < 16; cb += CHB) {
    __syncthreads();
    for (int e = tid; e < CHB*TT*324; e += 256) {
      int c = e / (TT*324), r3 = e - c*(TT*324);
      int tt = r3 / 324, r2 = r3 - tt*324;
      int r = r2 / 18, cc = r2 - r*18;
      int gh = min(max(h0 + r - 1, 0), HH-1);
      int gw = min(max(w0 + cc - 1, 0), WW-1);
      xt[e] = x[((size_t)(bi*CC + cig + cb + c)*TT + tt)*HW + gh*WW + gw];
    }
    __syncthreads();
    #pragma unroll
    for (int c = 0; c < CHB; ++c) {
      float acc = 0.f;
      #pragma unroll
      for (int tt = 0; tt < TT; ++tt)
        #pragma unroll
        for (int i = 0; i < 3; ++i)
          #pragma unroll
          for (int j = 0; j < 3; ++j)
            acc = fmaf(xt[c*(TT*324) + tt*324 + (th+i)*18 + tw + j],
                       kv[tt*9 + i*3 + j], acc);
      out[((size_t)(bi*CC + cig + cb + c))*HW + pix] = acc;
    }
  }
}

extern "C" void kernel_launch(void* const* d_in, const int* in_sizes, int n_in,
                              void* d_out, int out_size, void* d_ws, size_t ws_size,
                              hipStream_t stream) {
  const float* x  = (const float*)d_in[0];
  const float* w1 = (const float*)d_in[1];
  const float* b1 = (const float*)d_in[2];
  const float* w2 = (const float*)d_in[3];
  const float* b2 = (const float*)d_in[4];
  float* out = (float*)d_out;

  float* y    = (float*)d_ws;                       // 10*64*16384 fp32 = 40 MiB
  float* ker0 = y + (size_t)10*CC*HW;               // 10*9*16384 fp32 = 5.6 MiB

  conv1_k<<<dim3(8,8,40), dim3(16,16), 0, stream>>>(x, w1, b1, y);
  conv2_k<<<dim3(8,8,10), dim3(16,16), 0, stream>>>(y, w2, b2, ker0);
  dynf_k <<<dim3(8,8, 8), dim3(16,16), 0, stream>>>(x, ker0, out);
}

// Round 3
// 166.905 us; speedup vs baseline: 4.4475x; 4.4475x over previous
//
#include <hip/hip_runtime.h>
#include <hip/hip_bf16.h>

#define HH 128
#define WW 128
#define CC 64
#define TT 5
#define HW (HH*WW)
#define NI 10

typedef __attribute__((ext_vector_type(8))) short short8;
typedef __attribute__((ext_vector_type(4))) float f32x4;

__device__ __forceinline__ float bf2f(unsigned int bits16) {
  union { unsigned int u; float f; } v; v.u = bits16 << 16; return v.f;
}
__device__ __forceinline__ unsigned short f2bf(float f) {
  __hip_bfloat16 h = __float2bfloat16(f);
  return *reinterpret_cast<unsigned short*>(&h);
}

// ---- pack weights: wb1[oc][kk][ic] bf16 (64x9x64), wb2[oc16][kk][ic] (rows 9..15 = 0)
__global__ __launch_bounds__(256) void pack_w_k(const float* __restrict__ w1,
    const float* __restrict__ w2, unsigned short* __restrict__ wb1,
    unsigned short* __restrict__ wb2) {
  int idx = blockIdx.x*256 + threadIdx.x;
  if (idx < 64*576) {
    int oc = idx / 576, rem = idx - oc*576, kk = rem >> 6, ic = rem & 63;
    wb1[idx] = f2bf(w1[(oc*64 + ic)*9 + kk]);
  }
  if (idx < 16*576) {
    int oc = idx / 576, rem = idx - oc*576, kk = rem >> 6, ic = rem & 63;
    wb2[idx] = (oc < 9) ? f2bf(w2[(oc*64 + ic)*9 + kk]) : (unsigned short)0;
  }
}

// ---- pack x: xb[n=(bi,ti)][h][w][ci] bf16, via LDS transpose per (n,h) row
__global__ __launch_bounds__(256) void pack_x_k(const float* __restrict__ x,
    unsigned short* __restrict__ xb) {
  __shared__ unsigned short tb[128*72];   // row stride 72 keeps 16B chunks aligned
  const int tid = threadIdx.x;
  const int n = blockIdx.x >> 7, h = blockIdx.x & 127;
  const int bi = n / 5, ti = n - bi*5;
  const float* xp = x + ((size_t)bi*CC*TT + ti)*HW + (size_t)h*WW;
  for (int e = tid; e < 64*128; e += 256) {
    int ci = e >> 7, w = e & 127;
    tb[w*72 + ci] = f2bf(xp[(size_t)ci*TT*HW + w]);
  }
  __syncthreads();
  unsigned short* dst = xb + ((size_t)n*HW + (size_t)h*WW)*64;
  for (int e = tid; e < 1024; e += 256) {
    int w = e >> 3, c0 = (e & 7) << 3;
    uint4 v = *(const uint4*)(&tb[w*72 + c0]);
    *(uint4*)(&dst[w*64 + c0]) = v;
  }
}

// ---- conv1 implicit-GEMM MFMA: 16x16 pixel tile x 64 oc per block (4 waves)
// LDS xt[sp 0..324][ic 0..64] bf16, 16B chunks XOR-swizzled by (sp&7).
// K order: k = kk*64 + ic, split as (kk, half, q*8+j).
__global__ __launch_bounds__(256) void conv1_mfma(
    const unsigned short* __restrict__ xb, const unsigned short* __restrict__ wb1,
    const float* __restrict__ b1, unsigned short* __restrict__ yb) {
  __shared__ unsigned short xt[324*64];    // 41472 B
  const int tid = threadIdx.x;
  const int wave = tid >> 6, lane = tid & 63, q = lane >> 4, r = lane & 15;
  const int n = blockIdx.z, h0 = blockIdx.y << 4, w0 = blockIdx.x << 4;
  const unsigned short* xn = xb + (size_t)n*HW*64;

  for (int e = tid; e < 2592; e += 256) {           // 324 sp x 8 chunks
    int sp = e >> 3, c = e & 7;
    int sr = sp / 18, sc = sp - sr*18;
    int gh = h0 + sr - 1, gw = w0 + sc - 1;
    uint4 v = make_uint4(0u,0u,0u,0u);
    if (gh >= 0 && gh < HH && gw >= 0 && gw < WW)
      v = *(const uint4*)(xn + ((size_t)(gh*WW + gw))*64 + (c << 3));
    *(uint4*)(&xt[sp*64 + ((c ^ (sp & 7)) << 3)]) = v;
  }
  __syncthreads();

  f32x4 zero4 = {0.f, 0.f, 0.f, 0.f};
  f32x4 acc[4][4];                                   // [row i][oc group g]
  #pragma unroll
  for (int i = 0; i < 4; ++i)
    #pragma unroll
    for (int g = 0; g < 4; ++g) acc[i][g] = zero4;

  #pragma unroll
  for (int kk = 0; kk < 9; ++kk) {
    const int dy = kk / 3, dx = kk - dy*3;
    #pragma unroll
    for (int half = 0; half < 2; ++half) {
      short8 a[4];
      #pragma unroll
      for (int g = 0; g < 4; ++g)
        a[g] = *(const short8*)(wb1 + (g*16 + r)*576 + kk*64 + half*32 + (q << 3));
      #pragma unroll
      for (int i = 0; i < 4; ++i) {
        int sp = (wave*4 + i + dy)*18 + (r + dx);
        short8 b = *(const short8*)(&xt[sp*64 + ((((half << 2) | q) ^ (sp & 7)) << 3)]);
        #pragma unroll
        for (int g = 0; g < 4; ++g)
          acc[i][g] = __builtin_amdgcn_mfma_f32_16x16x32_bf16(a[g], b, acc[i][g], 0, 0, 0);
      }
    }
  }

  #pragma unroll
  for (int i = 0; i < 4; ++i) {
    int py = wave*4 + i;
    unsigned short* yp = yb + ((size_t)n*HW + (h0+py)*WW + (w0+r))*64;
    #pragma unroll
    for (int g = 0; g < 4; ++g) {
      int oc0 = g*16 + (q << 2);
      f32x4 bias = *(const f32x4*)(b1 + oc0);
      unsigned int p0, p1;
      float v0 = acc[i][g][0] + bias[0]; v0 = (v0 >= 0.f) ? v0 : 0.2f*v0;
      float v1 = acc[i][g][1] + bias[1]; v1 = (v1 >= 0.f) ? v1 : 0.2f*v1;
      float v2 = acc[i][g][2] + bias[2]; v2 = (v2 >= 0.f) ? v2 : 0.2f*v2;
      float v3 = acc[i][g][3] + bias[3]; v3 = (v3 >= 0.f) ? v3 : 0.2f*v3;
      p0 = (unsigned int)f2bf(v0) | ((unsigned int)f2bf(v1) << 16);
      p1 = (unsigned int)f2bf(v2) | ((unsigned int)f2bf(v3) << 16);
      uint2 pk; pk.x = p0; pk.y = p1;
      *(uint2*)(yp + oc0) = pk;
    }
  }
}

// ---- conv2 MFMA: 16x16 pixel tile, oc 0..8 (padded to 16), output fp32 ker0[n][oc][hw]
__global__ __launch_bounds__(256) void conv2_mfma(
    const unsigned short* __restrict__ yb, const unsigned short* __restrict__ wb2,
    const float* __restrict__ b2, float* __restrict__ ker0) {
  __shared__ unsigned short yt[324*64];
  const int tid = threadIdx.x;
  const int wave = tid >> 6, lane = tid & 63, q = lane >> 4, r = lane & 15;
  const int n = blockIdx.z, h0 = blockIdx.y << 4, w0 = blockIdx.x << 4;
  const unsigned short* yn = yb + (size_t)n*HW*64;

  for (int e = tid; e < 2592; e += 256) {
    int sp = e >> 3, c = e & 7;
    int sr = sp / 18, sc = sp - sr*18;
    int gh = h0 + sr - 1, gw = w0 + sc - 1;
    uint4 v = make_uint4(0u,0u,0u,0u);
    if (gh >= 0 && gh < HH && gw >= 0 && gw < WW)
      v = *(const uint4*)(yn + ((size_t)(gh*WW + gw))*64 + (c << 3));
    *(uint4*)(&yt[sp*64 + ((c ^ (sp & 7)) << 3)]) = v;
  }
  __syncthreads();

  f32x4 zero4 = {0.f, 0.f, 0.f, 0.f};
  f32x4 acc[4];
  #pragma unroll
  for (int i = 0; i < 4; ++i) acc[i] = zero4;

  #pragma unroll
  for (int kk = 0; kk < 9; ++kk) {
    const int dy = kk / 3, dx = kk - dy*3;
    #pragma unroll
    for (int half = 0; half < 2; ++half) {
      short8 a = *(const short8*)(wb2 + r*576 + kk*64 + half*32 + (q << 3));
      #pragma unroll
      for (int i = 0; i < 4; ++i) {
        int sp = (wave*4 + i + dy)*18 + (r + dx);
        short8 b = *(const short8*)(&yt[sp*64 + ((((half << 2) | q) ^ (sp & 7)) << 3)]);
        acc[i] = __builtin_amdgcn_mfma_f32_16x16x32_bf16(a, b, acc[i], 0, 0, 0);
      }
    }
  }

  #pragma unroll
  for (int i = 0; i < 4; ++i) {
    int py = wave*4 + i;
    #pragma unroll
    for (int t2 = 0; t2 < 4; ++t2) {
      int oc = (q << 2) + t2;
      if (oc < 9)
        ker0[((size_t)n*9 + oc)*HW + (h0+py)*WW + w0 + r] = acc[i][t2] + b2[oc];
    }
  }
}

// ---- dynamic filtering: 16x16 tile x 16 ci (quarter) per block.
// Per-thread kv[45] normalized in registers; x staged 4 ci at a time as fp32.
__global__ __launch_bounds__(256) void dynf_k(
    const unsigned short* __restrict__ xb, const float* __restrict__ ker0,
    float* __restrict__ out) {
  __shared__ float xs[TT*324*4];           // 25920 B
  const int tw = threadIdx.x, th = threadIdx.y;
  const int tid = th*16 + tw;
  const int wz = blockIdx.z;
  const int bi = wz >> 2, cq = wz & 3;
  const int h0 = blockIdx.y << 4, w0 = blockIdx.x << 4;
  const int pix = (h0+th)*WW + w0 + tw;

  float kv[45]; float s = 0.f;
  #pragma unroll
  for (int t5 = 0; t5 < TT; ++t5)
    #pragma unroll
    for (int kk = 0; kk < 9; ++kk) {
      float v = ker0[((size_t)(bi*TT + t5)*9 + kk)*HW + pix];
      kv[t5*9 + kk] = v; s += v;
    }
  const float m = (s - 1.f) * (1.f/45.f);   // mean - 1/45
  #pragma unroll
  for (int qq = 0; qq < 45; ++qq) kv[qq] -= m;

  for (int ch = 0; ch < 4; ++ch) {
    const int ci0 = cq*16 + ch*4;
    __syncthreads();
    for (int e = tid; e < TT*324; e += 256) {
      int t5 = e / 324, sp = e - t5*324;
      int rr = sp / 18, cc = sp - rr*18;
      int gh = min(max(h0 + rr - 1, 0), HH-1);
      int gw = min(max(w0 + cc - 1, 0), WW-1);
      uint2 raw = *(const uint2*)(xb + ((size_t)(bi*TT + t5)*HW + gh*WW + gw)*64 + ci0);
      f32x4 f;
      f[0] = bf2f(raw.x & 0xffffu);
      f[1] = bf2f(raw.x >> 16);
      f[2] = bf2f(raw.y & 0xffffu);
      f[3] = bf2f(raw.y >> 16);
      *(f32x4*)(&xs[e << 2]) = f;
    }
    __syncthreads();
    float a0 = 0.f, a1 = 0.f, a2 = 0.f, a3 = 0.f;
    #pragma unroll
    for (int t5 = 0; t5 < TT; ++t5)
      #pragma unroll
      for (int dy = 0; dy < 3; ++dy)
        #pragma unroll
        for (int dx = 0; dx < 3; ++dx) {
          f32x4 xv = *(const f32x4*)(&xs[(t5*324 + (th+dy)*18 + (tw+dx)) << 2]);
          float k = kv[t5*9 + dy*3 + dx];
          a0 = fmaf(xv[0], k, a0); a1 = fmaf(xv[1], k, a1);
          a2 = fmaf(xv[2], k, a2); a3 = fmaf(xv[3], k, a3);
        }
    float* op = out + ((size_t)(bi*CC + ci0))*HW + pix;
    op[0] = a0; op[HW] = a1; op[2*(size_t)HW] = a2; op[3*(size_t)HW] = a3;
  }
}

extern "C" void kernel_launch(void* const* d_in, const int* in_sizes, int n_in,
                              void* d_out, int out_size, void* d_ws, size_t ws_size,
                              hipStream_t stream) {
  const float* x  = (const float*)d_in[0];
  const float* w1 = (const float*)d_in[1];
  const float* b1 = (const float*)d_in[2];
  const float* w2 = (const float*)d_in[3];
  const float* b2 = (const float*)d_in[4];
  float* out = (float*)d_out;

  // workspace layout (bytes):
  unsigned short* xb  = (unsigned short*)d_ws;                 // 10*16384*64 bf16 = 20,971,520
  unsigned short* yb  = xb + (size_t)NI*HW*64;                 // same size
  float*          ker0 = (float*)(yb + (size_t)NI*HW*64);      // 10*9*16384 f32 = 5,898,240
  unsigned short* wb1 = (unsigned short*)(ker0 + (size_t)NI*9*HW); // 36864 bf16
  unsigned short* wb2 = wb1 + 64*576;                          // 9216 bf16

  pack_w_k <<<144, 256, 0, stream>>>(w1, w2, wb1, wb2);
  pack_x_k <<<NI*HH, 256, 0, stream>>>(x, xb);
  conv1_mfma<<<dim3(8,8,NI), 256, 0, stream>>>(xb, wb1, b1, yb);
  conv2_mfma<<<dim3(8,8,NI), 256, 0, stream>>>(yb, wb2, b2, ker0);
  dynf_k   <<<dim3(8,8,8), dim3(16,16), 0, stream>>>(xb, ker0, out);
}

// Round 4
// 156.662 us; speedup vs baseline: 4.7383x; 1.0654x over previous
//
#include <hip/hip_runtime.h>
#include <hip/hip_bf16.h>

#define HH 128
#define WW 128
#define CC 64
#define TT 5
#define HW (HH*WW)
#define NI 10

typedef __attribute__((ext_vector_type(8))) short short8;
typedef __attribute__((ext_vector_type(4))) float f32x4;

__device__ __forceinline__ float bf2f(unsigned int bits16) {
  union { unsigned int u; float f; } v; v.u = bits16 << 16; return v.f;
}
__device__ __forceinline__ unsigned short f2bf(float f) {
  __hip_bfloat16 h = __float2bfloat16(f);
  return *reinterpret_cast<unsigned short*>(&h);
}

// ---- pack weights: wb1[oc][kk][ic] bf16 (64x9x64), wb2[oc16][kk][ic] (rows 9..15 = 0)
__global__ __launch_bounds__(256) void pack_w_k(const float* __restrict__ w1,
    const float* __restrict__ w2, unsigned short* __restrict__ wb1,
    unsigned short* __restrict__ wb2) {
  int idx = blockIdx.x*256 + threadIdx.x;
  if (idx < 64*576) {
    int oc = idx / 576, rem = idx - oc*576, kk = rem >> 6, ic = rem & 63;
    wb1[idx] = f2bf(w1[(oc*64 + ic)*9 + kk]);
  }
  if (idx < 16*576) {
    int oc = idx / 576, rem = idx - oc*576, kk = rem >> 6, ic = rem & 63;
    wb2[idx] = (oc < 9) ? f2bf(w2[(oc*64 + ic)*9 + kk]) : (unsigned short)0;
  }
}

// ---- pack x: xb[n=(bi,ti)][h][w][ci] bf16, LDS transpose per (n,h) row.
// tb stride 68 shorts: write bank stride 34%32=2 (2-way, free); uint2 reads 8B-aligned.
__global__ __launch_bounds__(256) void pack_x_k(const float* __restrict__ x,
    unsigned short* __restrict__ xb) {
  __shared__ unsigned short tb[128*68];
  const int tid = threadIdx.x;
  const int n = blockIdx.x >> 7, h = blockIdx.x & 127;
  const int bi = n / 5, ti = n - bi*5;
  const float* xp = x + ((size_t)bi*CC*TT + ti)*HW + (size_t)h*WW;
  for (int e = tid; e < 64*128; e += 256) {
    int ci = e >> 7, w = e & 127;
    tb[w*68 + ci] = f2bf(xp[(size_t)ci*TT*HW + w]);
  }
  __syncthreads();
  unsigned short* dst = xb + ((size_t)n*HW + (size_t)h*WW)*64;
  for (int e = tid; e < 2048; e += 256) {
    int w = e >> 4, c = e & 15;
    *(uint2*)(dst + w*64 + c*4) = *(const uint2*)(&tb[w*68 + c*4]);
  }
}

// ---- conv1 implicit-GEMM MFMA v2: 128-thread blocks (2 waves), 16w x 8h tile,
// 32 oc per block. grid (8,16,20): z = n*2 + ocg. LDS 23 KB -> 6 blocks/CU.
__global__ __launch_bounds__(128, 3) void conv1_mfma(
    const unsigned short* __restrict__ xb, const unsigned short* __restrict__ wb1,
    const float* __restrict__ b1, unsigned short* __restrict__ yb) {
  __shared__ unsigned short xt[180*64];    // 10x18 halo x 64 ic = 23040 B
  const int tid = threadIdx.x;
  const int wave = tid >> 6, lane = tid & 63, q = lane >> 4, r = lane & 15;
  const int n = blockIdx.z >> 1, ocg = (blockIdx.z & 1) << 5;
  const int h0 = blockIdx.y << 3, w0 = blockIdx.x << 4;
  const unsigned short* xn = xb + (size_t)n*HW*64;

  for (int e = tid; e < 1440; e += 128) {           // 180 sp x 8 chunks
    int sp = e >> 3, c = e & 7;
    int sr = sp / 18, sc = sp - sr*18;
    int gh = h0 + sr - 1, gw = w0 + sc - 1;
    uint4 v = make_uint4(0u,0u,0u,0u);
    if (gh >= 0 && gh < HH && gw >= 0 && gw < WW)
      v = *(const uint4*)(xn + ((size_t)(gh*WW + gw))*64 + (c << 3));
    *(uint4*)(&xt[sp*64 + ((c ^ (sp & 7)) << 3)]) = v;
  }
  __syncthreads();

  f32x4 zero4 = {0.f, 0.f, 0.f, 0.f};
  f32x4 acc[4][2];                                   // [row i][oc group g]
  #pragma unroll
  for (int i = 0; i < 4; ++i)
    #pragma unroll
    for (int g = 0; g < 2; ++g) acc[i][g] = zero4;

  #pragma unroll
  for (int kk = 0; kk < 9; ++kk) {
    const int dy = kk / 3, dx = kk - dy*3;
    #pragma unroll
    for (int half = 0; half < 2; ++half) {
      short8 a0 = *(const short8*)(wb1 + (size_t)(ocg +      r)*576 + kk*64 + half*32 + (q << 3));
      short8 a1 = *(const short8*)(wb1 + (size_t)(ocg + 16 + r)*576 + kk*64 + half*32 + (q << 3));
      #pragma unroll
      for (int i = 0; i < 4; ++i) {
        int sp = (wave*4 + i + dy)*18 + (r + dx);
        short8 b = *(const short8*)(&xt[sp*64 + ((((half << 2) | q) ^ (sp & 7)) << 3)]);
        acc[i][0] = __builtin_amdgcn_mfma_f32_16x16x32_bf16(a0, b, acc[i][0], 0, 0, 0);
        acc[i][1] = __builtin_amdgcn_mfma_f32_16x16x32_bf16(a1, b, acc[i][1], 0, 0, 0);
      }
    }
  }

  #pragma unroll
  for (int i = 0; i < 4; ++i) {
    int py = wave*4 + i;
    unsigned short* yp = yb + ((size_t)n*HW + (h0+py)*WW + (w0+r))*64;
    #pragma unroll
    for (int g = 0; g < 2; ++g) {
      int oc0 = ocg + g*16 + (q << 2);
      f32x4 bias = *(const f32x4*)(b1 + oc0);
      float v0 = acc[i][g][0] + bias[0]; v0 = (v0 >= 0.f) ? v0 : 0.2f*v0;
      float v1 = acc[i][g][1] + bias[1]; v1 = (v1 >= 0.f) ? v1 : 0.2f*v1;
      float v2 = acc[i][g][2] + bias[2]; v2 = (v2 >= 0.f) ? v2 : 0.2f*v2;
      float v3 = acc[i][g][3] + bias[3]; v3 = (v3 >= 0.f) ? v3 : 0.2f*v3;
      uint2 pk;
      pk.x = (unsigned int)f2bf(v0) | ((unsigned int)f2bf(v1) << 16);
      pk.y = (unsigned int)f2bf(v2) | ((unsigned int)f2bf(v3) << 16);
      *(uint2*)(yp + oc0) = pk;
    }
  }
}

// ---- conv2 MFMA v2: 128-thread blocks, 16w x 8h tile, oc 0..8 (pad 16).
// grid (8,16,10). Output fp32 ker0[n][oc][hw].
__global__ __launch_bounds__(128, 3) void conv2_mfma(
    const unsigned short* __restrict__ yb, const unsigned short* __restrict__ wb2,
    const float* __restrict__ b2, float* __restrict__ ker0) {
  __shared__ unsigned short yt[180*64];
  const int tid = threadIdx.x;
  const int wave = tid >> 6, lane = tid & 63, q = lane >> 4, r = lane & 15;
  const int n = blockIdx.z;
  const int h0 = blockIdx.y << 3, w0 = blockIdx.x << 4;
  const unsigned short* yn = yb + (size_t)n*HW*64;

  for (int e = tid; e < 1440; e += 128) {
    int sp = e >> 3, c = e & 7;
    int sr = sp / 18, sc = sp - sr*18;
    int gh = h0 + sr - 1, gw = w0 + sc - 1;
    uint4 v = make_uint4(0u,0u,0u,0u);
    if (gh >= 0 && gh < HH && gw >= 0 && gw < WW)
      v = *(const uint4*)(yn + ((size_t)(gh*WW + gw))*64 + (c << 3));
    *(uint4*)(&yt[sp*64 + ((c ^ (sp & 7)) << 3)]) = v;
  }
  __syncthreads();

  f32x4 zero4 = {0.f, 0.f, 0.f, 0.f};
  f32x4 acc[4];
  #pragma unroll
  for (int i = 0; i < 4; ++i) acc[i] = zero4;

  #pragma unroll
  for (int kk = 0; kk < 9; ++kk) {
    const int dy = kk / 3, dx = kk - dy*3;
    #pragma unroll
    for (int half = 0; half < 2; ++half) {
      short8 a = *(const short8*)(wb2 + r*576 + kk*64 + half*32 + (q << 3));
      #pragma unroll
      for (int i = 0; i < 4; ++i) {
        int sp = (wave*4 + i + dy)*18 + (r + dx);
        short8 b = *(const short8*)(&yt[sp*64 + ((((half << 2) | q) ^ (sp & 7)) << 3)]);
        acc[i] = __builtin_amdgcn_mfma_f32_16x16x32_bf16(a, b, acc[i], 0, 0, 0);
      }
    }
  }

  #pragma unroll
  for (int i = 0; i < 4; ++i) {
    int py = wave*4 + i;
    #pragma unroll
    for (int t2 = 0; t2 < 4; ++t2) {
      int oc = (q << 2) + t2;
      if (oc < 9)
        ker0[((size_t)n*9 + oc)*HW + (h0+py)*WW + w0 + r] = acc[i][t2] + b2[oc];
    }
  }
}

// ---- dynamic filtering v2: 16x16 tile x 8 ci per block, grid (8,8,16).
// One barrier; 16 B global staging loads; two conflict-free fp32 planes in LDS.
__global__ __launch_bounds__(256, 3) void dynf_k(
    const unsigned short* __restrict__ xb, const float* __restrict__ ker0,
    float* __restrict__ out) {
  __shared__ float xs0[TT*324*4];          // ci0..3, 25920 B
  __shared__ float xs1[TT*324*4];          // ci4..7, 25920 B
  const int tw = threadIdx.x, th = threadIdx.y;
  const int tid = th*16 + tw;
  const int wz = blockIdx.z;
  const int bi = wz >> 3, ci0 = (wz & 7) << 3;
  const int h0 = blockIdx.y << 4, w0 = blockIdx.x << 4;
  const int pix = (h0+th)*WW + w0 + tw;

  float kv[45]; float s = 0.f;
  #pragma unroll
  for (int t5 = 0; t5 < TT; ++t5)
    #pragma unroll
    for (int kk = 0; kk < 9; ++kk) {
      float v = ker0[((size_t)(bi*TT + t5)*9 + kk)*HW + pix];
      kv[t5*9 + kk] = v; s += v;
    }
  const float m = (s - 1.f) * (1.f/45.f);   // mean - 1/45
  #pragma unroll
  for (int qq = 0; qq < 45; ++qq) kv[qq] -= m;

  for (int e = tid; e < TT*324; e += 256) {
    int t5 = e / 324, sp = e - t5*324;
    int rr = sp / 18, cc = sp - rr*18;
    int gh = min(max(h0 + rr - 1, 0), HH-1);
    int gw = min(max(w0 + cc - 1, 0), WW-1);
    uint4 raw = *(const uint4*)(xb + ((size_t)(bi*TT + t5)*HW + gh*WW + gw)*64 + ci0);
    xs0[(e << 2) + 0] = bf2f(raw.x & 0xffffu);
    xs0[(e << 2) + 1] = bf2f(raw.x >> 16);
    xs0[(e << 2) + 2] = bf2f(raw.y & 0xffffu);
    xs0[(e << 2) + 3] = bf2f(raw.y >> 16);
    xs1[(e << 2) + 0] = bf2f(raw.z & 0xffffu);
    xs1[(e << 2) + 1] = bf2f(raw.z >> 16);
    xs1[(e << 2) + 2] = bf2f(raw.w & 0xffffu);
    xs1[(e << 2) + 3] = bf2f(raw.w >> 16);
  }
  __syncthreads();

  #pragma unroll
  for (int p = 0; p < 2; ++p) {
    const float* plane = p ? xs1 : xs0;
    float a0 = 0.f, a1 = 0.f, a2 = 0.f, a3 = 0.f;
    #pragma unroll
    for (int t5 = 0; t5 < TT; ++t5)
      #pragma unroll
      for (int dy = 0; dy < 3; ++dy)
        #pragma unroll
        for (int dx = 0; dx < 3; ++dx) {
          f32x4 xv = *(const f32x4*)(&plane[(t5*324 + (th+dy)*18 + (tw+dx)) << 2]);
          float k = kv[t5*9 + dy*3 + dx];
          a0 = fmaf(xv[0], k, a0); a1 = fmaf(xv[1], k, a1);
          a2 = fmaf(xv[2], k, a2); a3 = fmaf(xv[3], k, a3);
        }
    float* op = out + ((size_t)(bi*CC + ci0 + p*4))*HW + pix;
    op[0] = a0; op[HW] = a1; op[2*(size_t)HW] = a2; op[3*(size_t)HW] = a3;
  }
}

extern "C" void kernel_launch(void* const* d_in, const int* in_sizes, int n_in,
                              void* d_out, int out_size, void* d_ws, size_t ws_size,
                              hipStream_t stream) {
  const float* x  = (const float*)d_in[0];
  const float* w1 = (const float*)d_in[1];
  const float* b1 = (const float*)d_in[2];
  const float* w2 = (const float*)d_in[3];
  const float* b2 = (const float*)d_in[4];
  float* out = (float*)d_out;

  unsigned short* xb  = (unsigned short*)d_ws;                 // 10*16384*64 bf16
  unsigned short* yb  = xb + (size_t)NI*HW*64;                 // same size
  float*          ker0 = (float*)(yb + (size_t)NI*HW*64);      // 10*9*16384 f32
  unsigned short* wb1 = (unsigned short*)(ker0 + (size_t)NI*9*HW);
  unsigned short* wb2 = wb1 + 64*576;

  pack_w_k  <<<144, 256, 0, stream>>>(w1, w2, wb1, wb2);
  pack_x_k  <<<NI*HH, 256, 0, stream>>>(x, xb);
  conv1_mfma<<<dim3(8,16,2*NI), 128, 0, stream>>>(xb, wb1, b1, yb);
  conv2_mfma<<<dim3(8,16,NI), 128, 0, stream>>>(yb, wb2, b2, ker0);
  dynf_k    <<<dim3(8,8,16), dim3(16,16), 0, stream>>>(xb, ker0, out);
}